// Round 3
// baseline (2111.520 us; speedup 1.0000x reference)
//
#include <hip/hip_runtime.h>
#include <cstdint>

// r_full[401][128]: rows 0..199 = coeff@bases, 200..399 = -(coeff@bases), 400 = self_rel
__global__ void k_rfull(const float* __restrict__ coeff, const float* __restrict__ bases,
                        const float* __restrict__ selfr, float* __restrict__ rfull) {
  int row = blockIdx.x, c = threadIdx.x;
  float v;
  if (row == 400) {
    v = selfr[c];
  } else {
    int rr = row < 200 ? row : row - 200;
    float s = 0.f;
#pragma unroll 10
    for (int b = 0; b < 50; ++b) s += coeff[rr * 50 + b] * bases[b * 128 + c];
    v = (row < 200) ? s : -s;
  }
  rfull[row * 128 + c] = v;
}

// out[r][c] = sum_k A[r][k]*B[k][c], K=128, N=128 (relation chain)
__global__ void k_rmm(const float* __restrict__ A, const float* __restrict__ B,
                      float* __restrict__ out) {
  int r = blockIdx.x, c = threadIdx.x;
  float s = 0.f;
#pragma unroll 8
  for (int k = 0; k < 128; ++k) s += A[r * 128 + k] * B[k * 128 + c];
  out[r * 128 + c] = s;
}

// scatter pass for class kcls: T[dst] += x[src] - r[type]  (only edges with y==kcls)
// one wave per edge, 2 floats per lane
__global__ void k_scatter(const float* __restrict__ x, const int* __restrict__ ids,
                          const float* __restrict__ r,
                          const int* __restrict__ ei, const int* __restrict__ et,
                          const int* __restrict__ y, float* __restrict__ T,
                          int nE, int kcls) {
  int gid = blockIdx.x * blockDim.x + threadIdx.x;
  int e = gid >> 6;
  if (e >= nE) return;
  if (y[e] != kcls) return;           // wave-uniform
  int lane = gid & 63;
  int src = ei[e], dst = ei[nE + e], t = et[e];
  if (ids) src = ids[src];
  int d = lane * 2;
  float2 hv = *(const float2*)&x[(size_t)src * 128 + d];
  float2 rv = *(const float2*)&r[(size_t)t * 128 + d];
  float* ap = &T[(size_t)dst * 128 + d];
  atomicAdd(ap, hv.x - rv.x);
  atomicAdd(ap + 1, hv.y - rv.y);
}

// C[M x 128] (+)= A[M x 128] @ B[128 x 128].  BM=64, BK=32, 256 thr, 8x4/thread
__global__ __launch_bounds__(256) void k_gemm128(const float* __restrict__ A,
                                                 const float* __restrict__ B,
                                                 float* __restrict__ C, int M, int init) {
  __shared__ float As[64][33];
  __shared__ float Bs[32][128];
  const int tid = threadIdx.x;
  const int m0 = blockIdx.x * 64;
  const int tx = tid & 31, ty = tid >> 5;
  float acc[8][4];
#pragma unroll
  for (int i = 0; i < 8; ++i)
#pragma unroll
    for (int j = 0; j < 4; ++j) acc[i][j] = 0.f;

  for (int kb = 0; kb < 128; kb += 32) {
    // A tile: 64 rows x 32 cols = 512 float4, 2 per thread
#pragma unroll
    for (int j = 0; j < 2; ++j) {
      int idx = tid + 256 * j;
      int r = idx >> 3, c4 = (idx & 7) * 4;
      int m = m0 + r;
      float4 v = make_float4(0.f, 0.f, 0.f, 0.f);
      if (m < M) v = *(const float4*)&A[(size_t)m * 128 + kb + c4];
      As[r][c4] = v.x; As[r][c4 + 1] = v.y; As[r][c4 + 2] = v.z; As[r][c4 + 3] = v.w;
    }
    // B tile: 32 rows x 128 cols = 1024 float4, 4 per thread
#pragma unroll
    for (int j = 0; j < 4; ++j) {
      int idx = tid + 256 * j;
      int kr = idx >> 5, c4 = (idx & 31) * 4;
      *(float4*)&Bs[kr][c4] = *(const float4*)&B[(size_t)(kb + kr) * 128 + c4];
    }
    __syncthreads();
#pragma unroll
    for (int kk = 0; kk < 32; ++kk) {
      float4 bv = *(const float4*)&Bs[kk][tx * 4];
#pragma unroll
      for (int i = 0; i < 8; ++i) {
        float a = As[ty + 8 * i][kk];
        acc[i][0] += a * bv.x; acc[i][1] += a * bv.y;
        acc[i][2] += a * bv.z; acc[i][3] += a * bv.w;
      }
    }
    __syncthreads();
  }
#pragma unroll
  for (int i = 0; i < 8; ++i) {
    int m = m0 + ty + 8 * i;
    if (m < M) {
      float4 v = make_float4(acc[i][0], acc[i][1], acc[i][2], acc[i][3]);
      if (!init) {
        float4 o = *(const float4*)&C[(size_t)m * 128 + tx * 4];
        v.x += o.x; v.y += o.y; v.z += o.z; v.w += o.w;
      }
      *(float4*)&C[(size_t)m * 128 + tx * 4] = v;
    }
  }
}

// per-column sum & sumsq over rows; 256 thr = 2 rows x 128 cols per iter
__global__ void k_stats(const float* __restrict__ agg, float* __restrict__ sums,
                        float* __restrict__ sumsq, int M) {
  int c = threadIdx.x & 127;
  int g = threadIdx.x >> 7;
  int row0 = blockIdx.x * 256;
  int rend = min(row0 + 256, M);
  float s = 0.f, q = 0.f;
  for (int r = row0 + g; r < rend; r += 2) {
    float v = agg[(size_t)r * 128 + c];
    s += v; q += v * v;
  }
  atomicAdd(&sums[c], s);
  atomicAdd(&sumsq[c], q);
}

__global__ void k_finalize(const float* __restrict__ sums, const float* __restrict__ sumsq,
                           const float* __restrict__ gamma, const float* __restrict__ beta,
                           float* __restrict__ scale, float* __restrict__ bias, float invN) {
  int c = threadIdx.x;
  float mean = sums[c] * invN;
  float var = fmaxf(sumsq[c] * invN - mean * mean, 0.f);
  float sc = rsqrtf(var + 1e-5f) * gamma[c];
  scale[c] = sc;
  bias[c] = beta[c] - mean * sc;
}

// in-place safe (elementwise)
__global__ void k_norm(const float* __restrict__ agg, const float* __restrict__ scale,
                       const float* __restrict__ bias, float* __restrict__ x, int total) {
  int idx = blockIdx.x * blockDim.x + threadIdx.x;
  if (idx >= total) return;
  int c = idx & 127;
  x[idx] = tanhf(fmaf(agg[idx], scale[c], bias[c]));
}

// one wave per triple: sum_d |x[h]+r[rel]-x[t]|
__global__ void k_score(const float* __restrict__ x, const float* __restrict__ r,
                        const int* __restrict__ triples, float* __restrict__ out, int nT) {
  int gid = blockIdx.x * blockDim.x + threadIdx.x;
  int t = gid >> 6;
  if (t >= nT) return;
  int lane = gid & 63;
  int h = triples[t * 3], rel = triples[t * 3 + 1], tl = triples[t * 3 + 2];
  int d = lane * 2;
  float2 a = *(const float2*)&x[(size_t)h * 128 + d];
  float2 b = *(const float2*)&r[(size_t)rel * 128 + d];
  float2 cc = *(const float2*)&x[(size_t)tl * 128 + d];
  float s = fabsf(a.x + b.x - cc.x) + fabsf(a.y + b.y - cc.y);
#pragma unroll
  for (int off = 32; off > 0; off >>= 1) s += __shfl_down(s, off);
  if (lane == 0) out[t] = s;
}

extern "C" void kernel_launch(void* const* d_in, const int* in_sizes, int n_in,
                              void* d_out, int out_size, void* d_ws, size_t ws_size,
                              hipStream_t stream) {
  const float* ent   = (const float*)d_in[0];
  const float* bases = (const float*)d_in[1];
  const float* coeff = (const float*)d_in[2];
  const float* selfr = (const float*)d_in[3];
  const float* W1    = (const float*)d_in[4];
  const float* relw1 = (const float*)d_in[5];
  const float* g1    = (const float*)d_in[6];
  const float* b1    = (const float*)d_in[7];
  const float* W2    = (const float*)d_in[8];
  const float* relw2 = (const float*)d_in[9];
  const float* g2    = (const float*)d_in[10];
  const float* b2    = (const float*)d_in[11];
  const int* ent_ids = (const int*)d_in[12];
  const int* ei      = (const int*)d_in[13];
  const int* et      = (const int*)d_in[14];
  const int* yk      = (const int*)d_in[15];
  const int* triples = (const int*)d_in[16];

  const int M  = in_sizes[0] / 128;   // 100000 entities
  const int nE = in_sizes[14];        // 800000 edges
  const int nT = in_sizes[16] / 3;    // 4096 triples

  // workspace layout (~154.2 MB total)
  float* p = (float*)d_ws;
  float* rfull = p; p += 401 * 128;
  float* r1    = p; p += 401 * 128;
  float* r2    = p; p += 401 * 128;
  float* T     = p; p += (size_t)M * 128;   // per-class scatter target
  float* agg1  = p; p += (size_t)M * 128;   // layer-1 agg -> x1 (in-place norm)
  float* agg2  = p; p += (size_t)M * 128;   // layer-2 agg -> x2 (in-place norm)
  float* sums  = p; p += 128;
  float* sumsq = p; p += 128;
  float* scale = p; p += 128;
  float* bias  = p; p += 128;

  float* out = (float*)d_out;

  const int scatBlocks = (nE * 64 + 255) / 256;
  const int gemmBlocks = (M + 63) / 64;
  const int statBlocks = (M + 255) / 256;
  const int total = M * 128;
  const int normBlocks = (total + 255) / 256;
  const size_t rowBytes = (size_t)M * 128 * sizeof(float);

  // relation chain (shared by both layers + scoring)
  k_rfull<<<401, 128, 0, stream>>>(coeff, bases, selfr, rfull);
  k_rmm<<<401, 128, 0, stream>>>(rfull, relw1, r1);
  k_rmm<<<401, 128, 0, stream>>>(r1, relw2, r2);

  // ---- layer 1: x_in = ent (via ent_ids), r = rfull, out -> agg1 ----
  for (int k = 0; k < 3; ++k) {
    hipMemsetAsync(T, 0, rowBytes, stream);
    k_scatter<<<scatBlocks, 256, 0, stream>>>(ent, ent_ids, rfull, ei, et, yk, T, nE, k);
    k_gemm128<<<gemmBlocks, 256, 0, stream>>>(T, W1 + (size_t)k * 16384, agg1, M, k == 0);
  }
  hipMemsetAsync(sums, 0, 256 * sizeof(float), stream);
  k_stats<<<statBlocks, 256, 0, stream>>>(agg1, sums, sumsq, M);
  k_finalize<<<1, 128, 0, stream>>>(sums, sumsq, g1, b1, scale, bias, 1.0f / M);
  k_norm<<<normBlocks, 256, 0, stream>>>(agg1, scale, bias, agg1, total);   // agg1 -> x1

  // ---- layer 2: x_in = agg1 (=x1), r = r1, out -> agg2 ----
  for (int k = 0; k < 3; ++k) {
    hipMemsetAsync(T, 0, rowBytes, stream);
    k_scatter<<<scatBlocks, 256, 0, stream>>>(agg1, nullptr, r1, ei, et, yk, T, nE, k);
    k_gemm128<<<gemmBlocks, 256, 0, stream>>>(T, W2 + (size_t)k * 16384, agg2, M, k == 0);
  }
  hipMemsetAsync(sums, 0, 256 * sizeof(float), stream);
  k_stats<<<statBlocks, 256, 0, stream>>>(agg2, sums, sumsq, M);
  k_finalize<<<1, 128, 0, stream>>>(sums, sumsq, g2, b2, scale, bias, 1.0f / M);
  k_norm<<<normBlocks, 256, 0, stream>>>(agg2, scale, bias, agg2, total);   // agg2 -> x2

  // ---- scoring ----
  k_score<<<(nT * 64 + 255) / 256, 256, 0, stream>>>(agg2, r2, triples, out, nT);
}

// Round 4
// 1604.540 us; speedup vs baseline: 1.3160x; 1.3160x over previous
//
#include <hip/hip_runtime.h>
#include <cstdint>

// r_full[401][128]: rows 0..199 = coeff@bases, 200..399 = -(coeff@bases), 400 = self_rel
__global__ void k_rfull(const float* __restrict__ coeff, const float* __restrict__ bases,
                        const float* __restrict__ selfr, float* __restrict__ rfull) {
  int row = blockIdx.x, c = threadIdx.x;
  float v;
  if (row == 400) {
    v = selfr[c];
  } else {
    int rr = row < 200 ? row : row - 200;
    float s = 0.f;
#pragma unroll 10
    for (int b = 0; b < 50; ++b) s += coeff[rr * 50 + b] * bases[b * 128 + c];
    v = (row < 200) ? s : -s;
  }
  rfull[row * 128 + c] = v;
}

// out[r][c] = sum_k A[r][k]*B[k][c], K=128, N=128 (relation chain)
__global__ void k_rmm(const float* __restrict__ A, const float* __restrict__ B,
                      float* __restrict__ out) {
  int r = blockIdx.x, c = threadIdx.x;
  float s = 0.f;
#pragma unroll 8
  for (int k = 0; k < 128; ++k) s += A[r * 128 + k] * B[k * 128 + c];
  out[r * 128 + c] = s;
}

// ---- CSR build over (dst, class) keys ----
__global__ void k_hist(const int* __restrict__ ei, const int* __restrict__ y,
                       int* __restrict__ counts, int nE) {
  int e = blockIdx.x * blockDim.x + threadIdx.x;
  if (e >= nE) return;
  int dst = ei[nE + e], k = y[e];
  atomicAdd(&counts[dst * 3 + k], 1);
}

// single-block chunked exclusive scan; writes offsets[0..n] and cursor[0..n-1]
__global__ void k_scan(const int* __restrict__ counts, int* __restrict__ offsets,
                       int* __restrict__ cursor, int n) {
  __shared__ int sdata[1024];
  __shared__ int carry_s;
  int tid = threadIdx.x;
  if (tid == 0) carry_s = 0;
  __syncthreads();
  for (int base = 0; base < n; base += 1024) {
    int i = base + tid;
    int v = (i < n) ? counts[i] : 0;
    sdata[tid] = v;
    __syncthreads();
    for (int off = 1; off < 1024; off <<= 1) {
      int t = (tid >= off) ? sdata[tid - off] : 0;
      __syncthreads();
      sdata[tid] += t;
      __syncthreads();
    }
    int inc = sdata[tid];
    int carry = carry_s;
    if (i < n) {
      int ex = carry + inc - v;
      offsets[i] = ex;
      cursor[i] = ex;
    }
    __syncthreads();
    if (tid == 1023) carry_s = carry + inc;
    __syncthreads();
  }
  if (tid == 0) offsets[n] = carry_s;
}

__global__ void k_fill(const int* __restrict__ ei, const int* __restrict__ y,
                       int* __restrict__ cursor, int* __restrict__ bucket, int nE) {
  int e = blockIdx.x * blockDim.x + threadIdx.x;
  if (e >= nE) return;
  int dst = ei[nE + e], k = y[e];
  int slot = atomicAdd(&cursor[dst * 3 + k], 1);
  bucket[slot] = e;
}

// one wave per dst: T[dst][c] = sum over class-kcls in-edges of (x[src][c] - r[type][c])
// 64 threads, float2 per lane. Non-atomic store; fully overwrites T.
__global__ void k_agg(const float* __restrict__ x, const int* __restrict__ ids,
                      const float* __restrict__ r,
                      const int* __restrict__ ei, const int* __restrict__ et,
                      const int* __restrict__ offsets, const int* __restrict__ bucket,
                      float* __restrict__ T, int nE, int kcls) {
  int dst = blockIdx.x;
  int c = threadIdx.x * 2;
  int s = offsets[dst * 3 + kcls];
  int e = offsets[dst * 3 + kcls + 1];
  float ax = 0.f, ay = 0.f;
  for (int j = s; j < e; ++j) {
    int ed = bucket[j];
    int src = ei[ed];
    if (ids) src = ids[src];
    int t = et[ed];
    float2 hv = *(const float2*)&x[(size_t)src * 128 + c];
    float2 rv = *(const float2*)&r[(size_t)t * 128 + c];
    ax += hv.x - rv.x;
    ay += hv.y - rv.y;
  }
  float2 o = make_float2(ax, ay);
  *(float2*)&T[(size_t)dst * 128 + c] = o;
}

// C[M x 128] (+)= A[M x 128] @ B[128 x 128].  BM=64, BK=32, 256 thr, 8x4/thread
__global__ __launch_bounds__(256) void k_gemm128(const float* __restrict__ A,
                                                 const float* __restrict__ B,
                                                 float* __restrict__ C, int M, int init) {
  __shared__ float As[64][33];
  __shared__ float Bs[32][128];
  const int tid = threadIdx.x;
  const int m0 = blockIdx.x * 64;
  const int tx = tid & 31, ty = tid >> 5;
  float acc[8][4];
#pragma unroll
  for (int i = 0; i < 8; ++i)
#pragma unroll
    for (int j = 0; j < 4; ++j) acc[i][j] = 0.f;

  for (int kb = 0; kb < 128; kb += 32) {
#pragma unroll
    for (int j = 0; j < 2; ++j) {
      int idx = tid + 256 * j;
      int r = idx >> 3, c4 = (idx & 7) * 4;
      int m = m0 + r;
      float4 v = make_float4(0.f, 0.f, 0.f, 0.f);
      if (m < M) v = *(const float4*)&A[(size_t)m * 128 + kb + c4];
      As[r][c4] = v.x; As[r][c4 + 1] = v.y; As[r][c4 + 2] = v.z; As[r][c4 + 3] = v.w;
    }
#pragma unroll
    for (int j = 0; j < 4; ++j) {
      int idx = tid + 256 * j;
      int kr = idx >> 5, c4 = (idx & 31) * 4;
      *(float4*)&Bs[kr][c4] = *(const float4*)&B[(size_t)(kb + kr) * 128 + c4];
    }
    __syncthreads();
#pragma unroll
    for (int kk = 0; kk < 32; ++kk) {
      float4 bv = *(const float4*)&Bs[kk][tx * 4];
#pragma unroll
      for (int i = 0; i < 8; ++i) {
        float a = As[ty + 8 * i][kk];
        acc[i][0] += a * bv.x; acc[i][1] += a * bv.y;
        acc[i][2] += a * bv.z; acc[i][3] += a * bv.w;
      }
    }
    __syncthreads();
  }
#pragma unroll
  for (int i = 0; i < 8; ++i) {
    int m = m0 + ty + 8 * i;
    if (m < M) {
      float4 v = make_float4(acc[i][0], acc[i][1], acc[i][2], acc[i][3]);
      if (!init) {
        float4 o = *(const float4*)&C[(size_t)m * 128 + tx * 4];
        v.x += o.x; v.y += o.y; v.z += o.z; v.w += o.w;
      }
      *(float4*)&C[(size_t)m * 128 + tx * 4] = v;
    }
  }
}

// per-column sum & sumsq over rows; 256 thr = 2 rows x 128 cols per iter
__global__ void k_stats(const float* __restrict__ agg, float* __restrict__ sums,
                        float* __restrict__ sumsq, int M) {
  int c = threadIdx.x & 127;
  int g = threadIdx.x >> 7;
  int row0 = blockIdx.x * 256;
  int rend = min(row0 + 256, M);
  float s = 0.f, q = 0.f;
  for (int r = row0 + g; r < rend; r += 2) {
    float v = agg[(size_t)r * 128 + c];
    s += v; q += v * v;
  }
  atomicAdd(&sums[c], s);
  atomicAdd(&sumsq[c], q);
}

__global__ void k_finalize(const float* __restrict__ sums, const float* __restrict__ sumsq,
                           const float* __restrict__ gamma, const float* __restrict__ beta,
                           float* __restrict__ scale, float* __restrict__ bias, float invN) {
  int c = threadIdx.x;
  float mean = sums[c] * invN;
  float var = fmaxf(sumsq[c] * invN - mean * mean, 0.f);
  float sc = rsqrtf(var + 1e-5f) * gamma[c];
  scale[c] = sc;
  bias[c] = beta[c] - mean * sc;
}

__global__ void k_norm(const float* __restrict__ agg, const float* __restrict__ scale,
                       const float* __restrict__ bias, float* __restrict__ x, int total) {
  int idx = blockIdx.x * blockDim.x + threadIdx.x;
  if (idx >= total) return;
  int c = idx & 127;
  x[idx] = tanhf(fmaf(agg[idx], scale[c], bias[c]));
}

// one wave per triple: sum_d |x[h]+r[rel]-x[t]|
__global__ void k_score(const float* __restrict__ x, const float* __restrict__ r,
                        const int* __restrict__ triples, float* __restrict__ out, int nT) {
  int gid = blockIdx.x * blockDim.x + threadIdx.x;
  int t = gid >> 6;
  if (t >= nT) return;
  int lane = gid & 63;
  int h = triples[t * 3], rel = triples[t * 3 + 1], tl = triples[t * 3 + 2];
  int d = lane * 2;
  float2 a = *(const float2*)&x[(size_t)h * 128 + d];
  float2 b = *(const float2*)&r[(size_t)rel * 128 + d];
  float2 cc = *(const float2*)&x[(size_t)tl * 128 + d];
  float s = fabsf(a.x + b.x - cc.x) + fabsf(a.y + b.y - cc.y);
#pragma unroll
  for (int off = 32; off > 0; off >>= 1) s += __shfl_down(s, off);
  if (lane == 0) out[t] = s;
}

extern "C" void kernel_launch(void* const* d_in, const int* in_sizes, int n_in,
                              void* d_out, int out_size, void* d_ws, size_t ws_size,
                              hipStream_t stream) {
  const float* ent   = (const float*)d_in[0];
  const float* bases = (const float*)d_in[1];
  const float* coeff = (const float*)d_in[2];
  const float* selfr = (const float*)d_in[3];
  const float* W1    = (const float*)d_in[4];
  const float* relw1 = (const float*)d_in[5];
  const float* g1    = (const float*)d_in[6];
  const float* b1    = (const float*)d_in[7];
  const float* W2    = (const float*)d_in[8];
  const float* relw2 = (const float*)d_in[9];
  const float* g2    = (const float*)d_in[10];
  const float* b2    = (const float*)d_in[11];
  const int* ent_ids = (const int*)d_in[12];
  const int* ei      = (const int*)d_in[13];
  const int* et      = (const int*)d_in[14];
  const int* yk      = (const int*)d_in[15];
  const int* triples = (const int*)d_in[16];

  const int M  = in_sizes[0] / 128;   // 100000 entities
  const int nE = in_sizes[14];        // 800000 edges
  const int nT = in_sizes[16] / 3;    // 4096 triples
  const int nKeys = M * 3;

  // workspace layout (~161.5 MB)
  float* p = (float*)d_ws;
  float* rfull = p; p += 401 * 128;
  float* r1    = p; p += 401 * 128;
  float* r2    = p; p += 401 * 128;
  float* T     = p; p += (size_t)M * 128;   // per-class segment sums
  float* agg1  = p; p += (size_t)M * 128;   // layer-1 agg -> x1 (in-place norm)
  float* agg2  = p; p += (size_t)M * 128;   // layer-2 agg -> x2 (in-place norm)
  float* sums  = p; p += 128;
  float* sumsq = p; p += 128;
  float* scale = p; p += 128;
  float* bias  = p; p += 128;
  int* counts  = (int*)p;          // nKeys
  int* offsets = counts + nKeys;   // nKeys + 1
  int* cursor  = offsets + nKeys + 1;  // nKeys
  int* bucket  = cursor + nKeys;   // nE

  float* out = (float*)d_out;

  const int gemmBlocks = (M + 63) / 64;
  const int statBlocks = (M + 255) / 256;
  const int total = M * 128;
  const int normBlocks = (total + 255) / 256;
  const int edgeBlocks = (nE + 255) / 256;

  // relation chain (shared by both layers + scoring)
  k_rfull<<<401, 128, 0, stream>>>(coeff, bases, selfr, rfull);
  k_rmm<<<401, 128, 0, stream>>>(rfull, relw1, r1);
  k_rmm<<<401, 128, 0, stream>>>(r1, relw2, r2);

  // CSR over (dst, class) — same graph both layers
  hipMemsetAsync(counts, 0, (size_t)nKeys * sizeof(int), stream);
  k_hist<<<edgeBlocks, 256, 0, stream>>>(ei, yk, counts, nE);
  k_scan<<<1, 1024, 0, stream>>>(counts, offsets, cursor, nKeys);
  k_fill<<<edgeBlocks, 256, 0, stream>>>(ei, yk, cursor, bucket, nE);

  // ---- layer 1: x_in = ent (via ent_ids), r = rfull, out -> agg1 ----
  for (int k = 0; k < 3; ++k) {
    k_agg<<<M, 64, 0, stream>>>(ent, ent_ids, rfull, ei, et, offsets, bucket, T, nE, k);
    k_gemm128<<<gemmBlocks, 256, 0, stream>>>(T, W1 + (size_t)k * 16384, agg1, M, k == 0);
  }
  hipMemsetAsync(sums, 0, 256 * sizeof(float), stream);
  k_stats<<<statBlocks, 256, 0, stream>>>(agg1, sums, sumsq, M);
  k_finalize<<<1, 128, 0, stream>>>(sums, sumsq, g1, b1, scale, bias, 1.0f / M);
  k_norm<<<normBlocks, 256, 0, stream>>>(agg1, scale, bias, agg1, total);   // agg1 -> x1

  // ---- layer 2: x_in = agg1 (=x1), r = r1, out -> agg2 ----
  for (int k = 0; k < 3; ++k) {
    k_agg<<<M, 64, 0, stream>>>(agg1, nullptr, r1, ei, et, offsets, bucket, T, nE, k);
    k_gemm128<<<gemmBlocks, 256, 0, stream>>>(T, W2 + (size_t)k * 16384, agg2, M, k == 0);
  }
  hipMemsetAsync(sums, 0, 256 * sizeof(float), stream);
  k_stats<<<statBlocks, 256, 0, stream>>>(agg2, sums, sumsq, M);
  k_finalize<<<1, 128, 0, stream>>>(sums, sumsq, g2, b2, scale, bias, 1.0f / M);
  k_norm<<<normBlocks, 256, 0, stream>>>(agg2, scale, bias, agg2, total);   // agg2 -> x2

  // ---- scoring ----
  k_score<<<(nT * 64 + 255) / 256, 256, 0, stream>>>(agg2, r2, triples, out, nT);
}

// Round 5
// 1078.006 us; speedup vs baseline: 1.9587x; 1.4884x over previous
//
#include <hip/hip_runtime.h>
#include <cstdint>

// r_full[401][128]: rows 0..199 = coeff@bases, 200..399 = -(coeff@bases), 400 = self_rel
__global__ void k_rfull(const float* __restrict__ coeff, const float* __restrict__ bases,
                        const float* __restrict__ selfr, float* __restrict__ rfull) {
  int row = blockIdx.x, c = threadIdx.x;
  float v;
  if (row == 400) {
    v = selfr[c];
  } else {
    int rr = row < 200 ? row : row - 200;
    float s = 0.f;
#pragma unroll 10
    for (int b = 0; b < 50; ++b) s += coeff[rr * 50 + b] * bases[b * 128 + c];
    v = (row < 200) ? s : -s;
  }
  rfull[row * 128 + c] = v;
}

// out[r][c] = sum_k A[r][k]*B[k][c], K=128, N=128 (relation chain)
__global__ void k_rmm(const float* __restrict__ A, const float* __restrict__ B,
                      float* __restrict__ out) {
  int r = blockIdx.x, c = threadIdx.x;
  float s = 0.f;
#pragma unroll 8
  for (int k = 0; k < 128; ++k) s += A[r * 128 + k] * B[k * 128 + c];
  out[r * 128 + c] = s;
}

// ---- CSR build over (dst, class) keys ----
__global__ void k_hist(const int* __restrict__ ei, const int* __restrict__ y,
                       int* __restrict__ counts, int nE) {
  int e = blockIdx.x * blockDim.x + threadIdx.x;
  if (e >= nE) return;
  int dst = ei[nE + e], k = y[e];
  atomicAdd(&counts[dst * 3 + k], 1);
}

// phase 1: per-block exclusive scan (block-local), block total out
__global__ void k_scan1(const int* __restrict__ counts, int* __restrict__ local,
                        int* __restrict__ blockSums, int n) {
  __shared__ int sdata[1024];
  int tid = threadIdx.x;
  int i = blockIdx.x * 1024 + tid;
  int v = (i < n) ? counts[i] : 0;
  sdata[tid] = v;
  __syncthreads();
#pragma unroll
  for (int off = 1; off < 1024; off <<= 1) {
    int t = (tid >= off) ? sdata[tid - off] : 0;
    __syncthreads();
    sdata[tid] += t;
    __syncthreads();
  }
  if (i < n) local[i] = sdata[tid] - v;   // block-local exclusive
  if (tid == 1023) blockSums[blockIdx.x] = sdata[1023];
}

// phase 2: single block scans block totals (nb <= 1024), writes carries + total
__global__ void k_scan2(const int* __restrict__ blockSums, int* __restrict__ carries,
                        int* __restrict__ offsets, int n, int nb) {
  __shared__ int sdata[1024];
  int tid = threadIdx.x;
  int v = (tid < nb) ? blockSums[tid] : 0;
  sdata[tid] = v;
  __syncthreads();
#pragma unroll
  for (int off = 1; off < 1024; off <<= 1) {
    int t = (tid >= off) ? sdata[tid - off] : 0;
    __syncthreads();
    sdata[tid] += t;
    __syncthreads();
  }
  if (tid < nb) carries[tid] = sdata[tid] - v;  // exclusive carry per block
  if (tid == 1023) offsets[n] = sdata[1023];    // grand total
}

// phase 3: add carry, write offsets + cursor copy
__global__ void k_scan3(const int* __restrict__ local, const int* __restrict__ carries,
                        int* __restrict__ offsets, int* __restrict__ cursor, int n) {
  int i = blockIdx.x * 1024 + threadIdx.x;
  if (i >= n) return;
  int v = local[i] + carries[blockIdx.x];
  offsets[i] = v;
  cursor[i] = v;
}

__global__ void k_fill(const int* __restrict__ ei, const int* __restrict__ y,
                       int* __restrict__ cursor, int* __restrict__ bucket, int nE) {
  int e = blockIdx.x * blockDim.x + threadIdx.x;
  if (e >= nE) return;
  int dst = ei[nE + e], k = y[e];
  int slot = atomicAdd(&cursor[dst * 3 + k], 1);
  bucket[slot] = e;
}

// one wave per dst: T[dst][c] = sum over class-kcls in-edges of (x[src][c] - r[type][c])
// 64 threads, float2 per lane. Non-atomic store; fully overwrites T.
__global__ void k_agg(const float* __restrict__ x, const int* __restrict__ ids,
                      const float* __restrict__ r,
                      const int* __restrict__ ei, const int* __restrict__ et,
                      const int* __restrict__ offsets, const int* __restrict__ bucket,
                      float* __restrict__ T, int nE, int kcls) {
  int dst = blockIdx.x;
  int c = threadIdx.x * 2;
  int s = offsets[dst * 3 + kcls];
  int e = offsets[dst * 3 + kcls + 1];
  float ax = 0.f, ay = 0.f;
  for (int j = s; j < e; ++j) {
    int ed = bucket[j];
    int src = ei[ed];
    if (ids) src = ids[src];
    int t = et[ed];
    float2 hv = *(const float2*)&x[(size_t)src * 128 + c];
    float2 rv = *(const float2*)&r[(size_t)t * 128 + c];
    ax += hv.x - rv.x;
    ay += hv.y - rv.y;
  }
  float2 o = make_float2(ax, ay);
  *(float2*)&T[(size_t)dst * 128 + c] = o;
}

// C[M x 128] (+)= A[M x 128] @ B[128 x 128].  BM=64, BK=32, 256 thr, 8x4/thread
__global__ __launch_bounds__(256) void k_gemm128(const float* __restrict__ A,
                                                 const float* __restrict__ B,
                                                 float* __restrict__ C, int M, int init) {
  __shared__ float As[64][33];
  __shared__ float Bs[32][128];
  const int tid = threadIdx.x;
  const int m0 = blockIdx.x * 64;
  const int tx = tid & 31, ty = tid >> 5;
  float acc[8][4];
#pragma unroll
  for (int i = 0; i < 8; ++i)
#pragma unroll
    for (int j = 0; j < 4; ++j) acc[i][j] = 0.f;

  for (int kb = 0; kb < 128; kb += 32) {
#pragma unroll
    for (int j = 0; j < 2; ++j) {
      int idx = tid + 256 * j;
      int r = idx >> 3, c4 = (idx & 7) * 4;
      int m = m0 + r;
      float4 v = make_float4(0.f, 0.f, 0.f, 0.f);
      if (m < M) v = *(const float4*)&A[(size_t)m * 128 + kb + c4];
      As[r][c4] = v.x; As[r][c4 + 1] = v.y; As[r][c4 + 2] = v.z; As[r][c4 + 3] = v.w;
    }
#pragma unroll
    for (int j = 0; j < 4; ++j) {
      int idx = tid + 256 * j;
      int kr = idx >> 5, c4 = (idx & 31) * 4;
      *(float4*)&Bs[kr][c4] = *(const float4*)&B[(size_t)(kb + kr) * 128 + c4];
    }
    __syncthreads();
#pragma unroll
    for (int kk = 0; kk < 32; ++kk) {
      float4 bv = *(const float4*)&Bs[kk][tx * 4];
#pragma unroll
      for (int i = 0; i < 8; ++i) {
        float a = As[ty + 8 * i][kk];
        acc[i][0] += a * bv.x; acc[i][1] += a * bv.y;
        acc[i][2] += a * bv.z; acc[i][3] += a * bv.w;
      }
    }
    __syncthreads();
  }
#pragma unroll
  for (int i = 0; i < 8; ++i) {
    int m = m0 + ty + 8 * i;
    if (m < M) {
      float4 v = make_float4(acc[i][0], acc[i][1], acc[i][2], acc[i][3]);
      if (!init) {
        float4 o = *(const float4*)&C[(size_t)m * 128 + tx * 4];
        v.x += o.x; v.y += o.y; v.z += o.z; v.w += o.w;
      }
      *(float4*)&C[(size_t)m * 128 + tx * 4] = v;
    }
  }
}

// per-column sum & sumsq over rows; 256 thr = 2 rows x 128 cols per iter
__global__ void k_stats(const float* __restrict__ agg, float* __restrict__ sums,
                        float* __restrict__ sumsq, int M) {
  int c = threadIdx.x & 127;
  int g = threadIdx.x >> 7;
  int row0 = blockIdx.x * 256;
  int rend = min(row0 + 256, M);
  float s = 0.f, q = 0.f;
  for (int r = row0 + g; r < rend; r += 2) {
    float v = agg[(size_t)r * 128 + c];
    s += v; q += v * v;
  }
  atomicAdd(&sums[c], s);
  atomicAdd(&sumsq[c], q);
}

__global__ void k_finalize(const float* __restrict__ sums, const float* __restrict__ sumsq,
                           const float* __restrict__ gamma, const float* __restrict__ beta,
                           float* __restrict__ scale, float* __restrict__ bias, float invN) {
  int c = threadIdx.x;
  float mean = sums[c] * invN;
  float var = fmaxf(sumsq[c] * invN - mean * mean, 0.f);
  float sc = rsqrtf(var + 1e-5f) * gamma[c];
  scale[c] = sc;
  bias[c] = beta[c] - mean * sc;
}

__global__ void k_norm(const float* __restrict__ agg, const float* __restrict__ scale,
                       const float* __restrict__ bias, float* __restrict__ x, int total) {
  int idx = blockIdx.x * blockDim.x + threadIdx.x;
  if (idx >= total) return;
  int c = idx & 127;
  x[idx] = tanhf(fmaf(agg[idx], scale[c], bias[c]));
}

// one wave per triple: sum_d |x[h]+r[rel]-x[t]|
__global__ void k_score(const float* __restrict__ x, const float* __restrict__ r,
                        const int* __restrict__ triples, float* __restrict__ out, int nT) {
  int gid = blockIdx.x * blockDim.x + threadIdx.x;
  int t = gid >> 6;
  if (t >= nT) return;
  int lane = gid & 63;
  int h = triples[t * 3], rel = triples[t * 3 + 1], tl = triples[t * 3 + 2];
  int d = lane * 2;
  float2 a = *(const float2*)&x[(size_t)h * 128 + d];
  float2 b = *(const float2*)&r[(size_t)rel * 128 + d];
  float2 cc = *(const float2*)&x[(size_t)tl * 128 + d];
  float s = fabsf(a.x + b.x - cc.x) + fabsf(a.y + b.y - cc.y);
#pragma unroll
  for (int off = 32; off > 0; off >>= 1) s += __shfl_down(s, off);
  if (lane == 0) out[t] = s;
}

extern "C" void kernel_launch(void* const* d_in, const int* in_sizes, int n_in,
                              void* d_out, int out_size, void* d_ws, size_t ws_size,
                              hipStream_t stream) {
  const float* ent   = (const float*)d_in[0];
  const float* bases = (const float*)d_in[1];
  const float* coeff = (const float*)d_in[2];
  const float* selfr = (const float*)d_in[3];
  const float* W1    = (const float*)d_in[4];
  const float* relw1 = (const float*)d_in[5];
  const float* g1    = (const float*)d_in[6];
  const float* b1    = (const float*)d_in[7];
  const float* W2    = (const float*)d_in[8];
  const float* relw2 = (const float*)d_in[9];
  const float* g2    = (const float*)d_in[10];
  const float* b2    = (const float*)d_in[11];
  const int* ent_ids = (const int*)d_in[12];
  const int* ei      = (const int*)d_in[13];
  const int* et      = (const int*)d_in[14];
  const int* yk      = (const int*)d_in[15];
  const int* triples = (const int*)d_in[16];

  const int M  = in_sizes[0] / 128;   // 100000 entities
  const int nE = in_sizes[14];        // 800000 edges
  const int nT = in_sizes[16] / 3;    // 4096 triples
  const int nKeys = M * 3;
  const int nScanBlocks = (nKeys + 1023) / 1024;  // 293

  // workspace layout (~161.5 MB)
  float* p = (float*)d_ws;
  float* rfull = p; p += 401 * 128;
  float* r1    = p; p += 401 * 128;
  float* r2    = p; p += 401 * 128;
  float* T     = p; p += (size_t)M * 128;   // per-class segment sums
  float* agg1  = p; p += (size_t)M * 128;   // layer-1 agg -> x1 (in-place norm)
  float* agg2  = p; p += (size_t)M * 128;   // layer-2 agg -> x2 (in-place norm)
  float* sums  = p; p += 128;
  float* sumsq = p; p += 128;
  float* scale = p; p += 128;
  float* bias  = p; p += 128;
  int* counts  = (int*)p;              // nKeys
  int* offsets = counts + nKeys;       // nKeys + 1
  int* cursor  = offsets + nKeys + 1;  // nKeys
  int* bucket  = cursor + nKeys;       // nE
  int* slocal  = bucket + nE;          // nKeys (scan scratch)
  int* sblock  = slocal + nKeys;       // nScanBlocks (block totals)
  int* scarry  = sblock + nScanBlocks; // nScanBlocks (block carries)

  float* out = (float*)d_out;

  const int gemmBlocks = (M + 63) / 64;
  const int statBlocks = (M + 255) / 256;
  const int total = M * 128;
  const int normBlocks = (total + 255) / 256;
  const int edgeBlocks = (nE + 255) / 256;

  // relation chain (shared by both layers + scoring)
  k_rfull<<<401, 128, 0, stream>>>(coeff, bases, selfr, rfull);
  k_rmm<<<401, 128, 0, stream>>>(rfull, relw1, r1);
  k_rmm<<<401, 128, 0, stream>>>(r1, relw2, r2);

  // CSR over (dst, class) — same graph both layers
  hipMemsetAsync(counts, 0, (size_t)nKeys * sizeof(int), stream);
  k_hist<<<edgeBlocks, 256, 0, stream>>>(ei, yk, counts, nE);
  k_scan1<<<nScanBlocks, 1024, 0, stream>>>(counts, slocal, sblock, nKeys);
  k_scan2<<<1, 1024, 0, stream>>>(sblock, scarry, offsets, nKeys, nScanBlocks);
  k_scan3<<<nScanBlocks, 1024, 0, stream>>>(slocal, scarry, offsets, cursor, nKeys);
  k_fill<<<edgeBlocks, 256, 0, stream>>>(ei, yk, cursor, bucket, nE);

  // ---- layer 1: x_in = ent (via ent_ids), r = rfull, out -> agg1 ----
  for (int k = 0; k < 3; ++k) {
    k_agg<<<M, 64, 0, stream>>>(ent, ent_ids, rfull, ei, et, offsets, bucket, T, nE, k);
    k_gemm128<<<gemmBlocks, 256, 0, stream>>>(T, W1 + (size_t)k * 16384, agg1, M, k == 0);
  }
  hipMemsetAsync(sums, 0, 256 * sizeof(float), stream);
  k_stats<<<statBlocks, 256, 0, stream>>>(agg1, sums, sumsq, M);
  k_finalize<<<1, 128, 0, stream>>>(sums, sumsq, g1, b1, scale, bias, 1.0f / M);
  k_norm<<<normBlocks, 256, 0, stream>>>(agg1, scale, bias, agg1, total);   // agg1 -> x1

  // ---- layer 2: x_in = agg1 (=x1), r = r1, out -> agg2 ----
  for (int k = 0; k < 3; ++k) {
    k_agg<<<M, 64, 0, stream>>>(agg1, nullptr, r1, ei, et, offsets, bucket, T, nE, k);
    k_gemm128<<<gemmBlocks, 256, 0, stream>>>(T, W2 + (size_t)k * 16384, agg2, M, k == 0);
  }
  hipMemsetAsync(sums, 0, 256 * sizeof(float), stream);
  k_stats<<<statBlocks, 256, 0, stream>>>(agg2, sums, sumsq, M);
  k_finalize<<<1, 128, 0, stream>>>(sums, sumsq, g2, b2, scale, bias, 1.0f / M);
  k_norm<<<normBlocks, 256, 0, stream>>>(agg2, scale, bias, agg2, total);   // agg2 -> x2

  // ---- scoring ----
  k_score<<<(nT * 64 + 255) / 256, 256, 0, stream>>>(agg2, r2, triples, out, nT);
}